// Round 1
// baseline (124.602 us; speedup 1.0000x reference)
//
#include <hip/hip_runtime.h>
#include <math.h>

#define BB 8
#define NN 2000
#define CC 81
#define NPAD 2048
#define MAXI 100
#define HH 512
#define WW 512

// ---------------------------------------------------------------------------
// Kernel A: per-proposal class argmax, delta refine, validity, sort key.
// [R4-proven bit-exact arithmetic; R10: packed 2xfloat4 output + rank pre-zero]
//   pkd[idx*2+0] = (y1,x1,y2,x2)   refined box
//   pkd[idx*2+1] = (score, cls_bits, valid_bits, 0)
// ---------------------------------------------------------------------------
__global__ void k_refine(const float* __restrict__ rois,
                         const float* __restrict__ probs,
                         const float* __restrict__ deltas,
                         const float* __restrict__ stdv,
                         float4* __restrict__ pkd, int* __restrict__ rnk,
                         unsigned long long* __restrict__ gkeys) {
#pragma clang fp contract(off)
  int g = blockIdx.x * 4 + (threadIdx.x >> 6);
  if (g >= BB * NPAD) return;
  int lane = threadIdx.x & 63;
  int b = g >> 11, n = g & (NPAD - 1);
  if (n >= NN) {                      // pad slot: sentinel key + invalid
    if (lane == 0) {
      int idx = b * NPAD + n;
      unsigned u = __float_as_uint(-INFINITY);
      u = ~u;                         // sign set -> ~u
      gkeys[idx] = ((unsigned long long)u << 32) | (0xFFFFFFFFu - (unsigned)n);
      // NMS may gather this slot's meta; box half stays poisoned (never used)
      pkd[idx * 2 + 1] = make_float4(0.f, __int_as_float(0), __int_as_float(0), 0.f);
      rnk[idx] = 0;                   // pre-zero for k_rankp atomicAdd
    }
    return;
  }
  const float* pp = probs + ((size_t)b * NN + n) * CC;
  float best = -INFINITY;
  int bc = CC;
  for (int c = lane; c < CC; c += 64) {
    float p = pp[c];
    if (p > best) { best = p; bc = c; }   // per-lane stride keeps first max
  }
  // cross-lane argmax, first-occurrence tie-break (smaller class wins)
  for (int off = 32; off; off >>= 1) {
    float ob = __shfl_xor(best, off, 64);
    int oc = __shfl_xor(bc, off, 64);
    if (ob > best || (ob == best && oc < bc)) { best = ob; bc = oc; }
  }
  if (lane == 0) {
    int idx = b * NPAD + n;
    const float* r = rois + ((size_t)b * NN + n) * 4;
    const float* dd = deltas + (((size_t)b * NN + n) * CC + bc) * 4;
    float d0 = dd[0] * stdv[0], d1 = dd[1] * stdv[1];
    float d2 = dd[2] * stdv[2], d3 = dd[3] * stdv[3];
    float y1 = r[0], x1 = r[1], y2 = r[2], x2 = r[3];
    float h = y2 - y1, w = x2 - x1;
    float cy = y1 + 0.5f * h + d0 * h;
    float cx = x1 + 0.5f * w + d1 * w;
    h = h * (float)exp((double)d2);   // double path ~= correctly-rounded f32 exp
    w = w * (float)exp((double)d3);
    float ny1 = cy - 0.5f * h, nx1 = cx - 0.5f * w;
    float ny2 = cy + 0.5f * h, nx2 = cx + 0.5f * w;
    ny1 = fminf(fmaxf(ny1, 0.f), 1.f);
    nx1 = fminf(fmaxf(nx1, 0.f), 1.f);
    ny2 = fminf(fmaxf(ny2, 0.f), 1.f);
    nx2 = fminf(fmaxf(nx2, 0.f), 1.f);
    int v = (bc > 0 && best >= 0.05f) ? 1 : 0;
    pkd[idx * 2 + 0] = make_float4(ny1, nx1, ny2, nx2);
    pkd[idx * 2 + 1] = make_float4(best, __int_as_float(bc), __int_as_float(v), 0.f);
    rnk[idx] = 0;                     // pre-zero for k_rankp atomicAdd
    float ks = v ? best : -INFINITY;
    unsigned u = __float_as_uint(ks);
    u = (u & 0x80000000u) ? ~u : (u | 0x80000000u);
    gkeys[idx] = ((unsigned long long)u << 32) | (0xFFFFFFFFu - (unsigned)n);
  }
}

// ---------------------------------------------------------------------------
// Kernel B: partial rank counts, CHIP-WIDE (512 blocks). [R4-proven counts]
// R10: accumulate straight into rnk[] via device-scope atomicAdd (8-way
// contention per address, integer sum is order-independent) — removes the
// 2 MB partial[] round-trip and 7/8 of k_permnms P0's global loads.
// ---------------------------------------------------------------------------
__global__ void k_rankp(const unsigned long long* __restrict__ gkeys,
                        int* __restrict__ rnk) {
  __shared__ unsigned long long sk[256];
  int blk = blockIdx.x;                 // b*64 + ip*8 + jp
  int jp = blk & 7, ip = (blk >> 3) & 7, b = blk >> 6;
  int tid = threadIdx.x;
  sk[tid] = gkeys[b * NPAD + jp * 256 + tid];
  unsigned long long myk = gkeys[b * NPAD + ip * 256 + tid];
  __syncthreads();
  int cnt = 0;
#pragma unroll 8
  for (int j = 0; j < 256; j++) cnt += (sk[j] > myk) ? 1 : 0;
  atomicAdd(&rnk[b * NPAD + ip * 256 + tid], cnt);
}

// ---------------------------------------------------------------------------
// Kernel C (v10): perm + mask-resolve NMS, 1 block of 1024 threads per batch.
//   P0+P1 fused: thread computing rank[e] stages candidate e directly when
//     rank<256. R10: rank is ONE coalesced load (was 8), candidate meta is
//     TWO contiguous float4 gathers (was 4 scattered arrays).
//   P2: STRICTLY-LOWER-TRIANGLE overlap bits. [R9-proven]
//   P3: wave 0 greedy resolve, one ballot per accept; parallel det/kept
//     writes; R10: also emits kbox4 sidecar for k_mask.
//   P4: rare serial continuation past candidate 256 (R7-proven loop).
// Same fp-contract-off IoU bits, union order, greedy order as reference.
// ---------------------------------------------------------------------------
__global__ void __launch_bounds__(1024)
k_permnms(const int* __restrict__ rnk, const float4* __restrict__ pkd,
          float* __restrict__ det, float4* __restrict__ kb4) {
#pragma clang fp contract(off)
  __shared__ int sperm[NPAD];
  __shared__ float4 spk4[256];      // offset box (oy1,ox1,oy2,ox2)
  __shared__ float sarea[256];
  __shared__ float4 sbox4[256];     // unoffset box (for det output)
  __shared__ float sscr[256];
  __shared__ int   scl[256];
  __shared__ int   sval[256];
  __shared__ unsigned long long smask[256][5];  // 4 words + pad
  __shared__ float4 kpk4[MAXI];     // kept offset boxes
  __shared__ float  karea[MAXI];
  __shared__ int s_kcount, s_need;

  int b = blockIdx.x, tid = threadIdx.x;
  int lane = tid & 63, wv = tid >> 6;

  if (tid == 0) { s_kcount = 0; s_need = 0; }
  // ---- P0+P1: rank load -> sperm; stage top-256 inline ----
  for (int e = tid; e < NPAD; e += 1024) {
    int rank = rnk[b * NPAD + e];
    sperm[rank] = e;
    if (rank < 256) {
      int o = b * NPAD + e;
      float4 bx = pkd[o * 2 + 0];
      float4 s1 = pkd[o * 2 + 1];
      float sc = s1.x;
      int c = __float_as_int(s1.y);
      int v = __float_as_int(s1.z);
      float off = 2.0f * (float)c;
      float oy1 = bx.x + off, ox1 = bx.y + off;
      float oy2 = bx.z + off, ox2 = bx.w + off;
      float ar = (oy2 - oy1) * (ox2 - ox1);
      if (!v) { oy1 = ox1 = oy2 = ox2 = 0.f; ar = 0.f; }  // inert
      spk4[rank] = make_float4(oy1, ox1, oy2, ox2);
      sarea[rank] = ar;
      sbox4[rank] = bx;
      sscr[rank] = sc; scl[rank] = c; sval[rank] = v;
    }
  }
  __syncthreads();

  // ---- P2: lower-triangle overlap bits; thread = (row i, j-word) ----
  {
    int i = tid & 255, jw = tid >> 8;
    int iw = i >> 6;
    unsigned long long m = 0ULL;
    if (jw <= iw) {                       // waves with jw>iw skip entirely
      float4 me = spk4[i];
      float ma = sarea[i];
      int j0 = jw * 64;
      int lim = (jw < iw) ? 64 : (i & 63);  // strictly j < i
#pragma unroll 4
      for (int jj = 0; jj < lim; jj++) {
        float4 ob = spk4[j0 + jj];
        float yy1 = fmaxf(me.x, ob.x), xx1 = fmaxf(me.y, ob.y);
        float yy2 = fminf(me.z, ob.z), xx2 = fminf(me.w, ob.w);
        float inter = fmaxf(yy2 - yy1, 0.f) * fmaxf(xx2 - xx1, 0.f);
        float uni = (ma + sarea[j0 + jj]) - inter;
        if (inter / fmaxf(uni, 1e-12f) > 0.3f) m |= 1ULL << jj;
      }
    }
    smask[i][jw] = m;
  }
  __syncthreads();

  // ---- P3: wave 0 greedy resolve + parallel writes ----
  if (wv == 0) {
    unsigned long long m[4][4];
    int vv[4];
    for (int s = 0; s < 4; s++) {
      int i = s * 64 + lane;
      m[s][0] = smask[i][0]; m[s][1] = smask[i][1];
      m[s][2] = smask[i][2]; m[s][3] = smask[i][3];
      vv[s] = sval[i];
    }
    bool all_valid = ((__ballot(vv[0] != 0) & __ballot(vv[1] != 0) &
                       __ballot(vv[2] != 0) & __ballot(vv[3] != 0)) == ~0ULL);
    unsigned long long acc[4] = {0ULL, 0ULL, 0ULL, 0ULL};
    int kcount = 0;
    bool stop = false;
    for (int s = 0; s < 4 && !stop; s++) {
      bool ok = vv[s] && (((m[s][0] & acc[0]) | (m[s][1] & acc[1]) |
                           (m[s][2] & acc[2]) | (m[s][3] & acc[3])) == 0ULL);
      unsigned long long bal = __ballot(ok);
      while (bal) {
        int o = __ffsll((unsigned long long)bal) - 1;  // lowest index = greedy
        acc[s] |= 1ULL << o;
        kcount++;
        if (kcount == MAXI) { stop = true; break; }
        ok = ok && !((m[s][s] >> o) & 1ULL) && (lane != o);
        bal = __ballot(ok);
      }
    }
    int prefix[4], run = 0;
    for (int s = 0; s < 4; s++) { prefix[s] = run; run += (int)__popcll(acc[s]); }
    for (int s = 0; s < 4; s++) {
      if ((acc[s] >> lane) & 1ULL) {
        int i = s * 64 + lane;
        int row = prefix[s] + (int)__popcll(acc[s] & ((1ULL << lane) - 1ULL));
        float4 bx = sbox4[i];
        float* dr = det + ((size_t)b * MAXI + row) * 6;
        dr[0] = bx.x; dr[1] = bx.y; dr[2] = bx.z; dr[3] = bx.w;
        dr[4] = (float)scl[i]; dr[5] = sscr[i];
        kb4[(size_t)b * MAXI + row] = bx;       // sidecar for k_mask
        kpk4[row] = spk4[i];
        karea[row] = sarea[i];
      }
    }
    if (lane == 0) {
      s_kcount = kcount;
      s_need = (kcount < MAXI && all_valid) ? 1 : 0;
    }
  }
  __syncthreads();

  // ---- P4: rare serial continuation past candidate 256 (wave 0) ----
  if (s_need && wv == 0) {
    int kept = s_kcount;
    float k0y1 = 0.f, k0x1 = 0.f, k0y2 = 0.f, k0x2 = 0.f, k0a = 0.f;
    float k1y1 = 0.f, k1x1 = 0.f, k1y2 = 0.f, k1x2 = 0.f, k1a = 0.f;
    if (lane < kept) {
      float4 t = kpk4[lane];
      k0y1 = t.x; k0x1 = t.y; k0y2 = t.z; k0x2 = t.w; k0a = karea[lane];
    }
    if (64 + lane < kept) {
      float4 t = kpk4[64 + lane];
      k1y1 = t.x; k1x1 = t.y; k1y2 = t.z; k1x2 = t.w; k1a = karea[64 + lane];
    }
    bool done = false;
    for (int base = 256; base < NN && !done; base += 64) {
      int pi = sperm[base + lane];
      int o = b * NPAD + pi;
      float4 bx = pkd[o * 2 + 0];
      float4 s1 = pkd[o * 2 + 1];
      int lv = __float_as_int(s1.z);
      int lc = __float_as_int(s1.y);
      float lsc = s1.x;
      int lim = (NN - base < 64) ? (NN - base) : 64;
      for (int j = 0; j < lim; j++) {
        int v = __shfl(lv, j, 64);
        if (!v) { done = true; break; }   // sorted: all invalid at the end
        float y1 = __shfl(bx.x, j, 64);
        float x1 = __shfl(bx.y, j, 64);
        float y2 = __shfl(bx.z, j, 64);
        float x2 = __shfl(bx.w, j, 64);
        int c = __shfl(lc, j, 64);
        float off = 2.0f * (float)c;
        float oy1 = y1 + off, ox1 = x1 + off, oy2 = y2 + off, ox2 = x2 + off;
        float area_i = (oy2 - oy1) * (ox2 - ox1);
        bool pred = false;
        if (lane < kept) {
          float yy1 = fmaxf(oy1, k0y1), xx1 = fmaxf(ox1, k0x1);
          float yy2 = fminf(oy2, k0y2), xx2 = fminf(ox2, k0x2);
          float inter = fmaxf(yy2 - yy1, 0.f) * fmaxf(xx2 - xx1, 0.f);
          float uni = (area_i + k0a) - inter;
          pred = (inter / fmaxf(uni, 1e-12f)) > 0.3f;
        }
        if (64 + lane < kept) {
          float yy1 = fmaxf(oy1, k1y1), xx1 = fmaxf(ox1, k1x1);
          float yy2 = fminf(oy2, k1y2), xx2 = fminf(ox2, k1x2);
          float inter = fmaxf(yy2 - yy1, 0.f) * fmaxf(xx2 - xx1, 0.f);
          float uni = (area_i + k1a) - inter;
          pred = pred || ((inter / fmaxf(uni, 1e-12f)) > 0.3f);
        }
        if (__ballot(pred) == 0ULL) {            // wave-uniform accept
          if (kept < 64) {
            if (lane == kept) { k0y1 = oy1; k0x1 = ox1; k0y2 = oy2; k0x2 = ox2; k0a = area_i; }
          } else {
            if (lane == kept - 64) { k1y1 = oy1; k1x1 = ox1; k1y2 = oy2; k1x2 = ox2; k1a = area_i; }
          }
          float sc = __shfl(lsc, j, 64);
          if (lane == 0) {
            float* dr = det + ((size_t)b * MAXI + kept) * 6;
            dr[0] = y1; dr[1] = x1; dr[2] = y2; dr[3] = x2;
            dr[4] = (float)c; dr[5] = sc;
            kb4[(size_t)b * MAXI + kept] = make_float4(y1, x1, y2, x2);
          }
          kept++;
          if (kept == MAXI) { done = true; break; }
        }
      }
    }
    if (lane == 0) s_kcount = kept;
  }
  __syncthreads();

  // ---- zero-fill remaining det rows + kbox4 tail (d_out/ws poisoned 0xAA) ----
  {
    int kc = s_kcount;
    int rem = (MAXI - kc) * 6;
    float* dr0 = det + ((size_t)b * MAXI + kc) * 6;
    for (int t = tid; t < rem; t += 1024) dr0[t] = 0.f;
    float4* kb = kb4 + (size_t)b * MAXI;
    for (int t = kc + tid; t < MAXI; t += 1024)
      kb[t] = make_float4(0.f, 0.f, 0.f, 0.f);
  }
}

// ---------------------------------------------------------------------------
// Kernel D: attention mask. One block per (batch, row); 256 threads,
// 2 pixels per thread; ballot+popcount compaction. [R4-proven bit-exact]
// R10: reads the aligned kbox4 sidecar (1 coalesced float4 per row) instead
// of 4 scalar 24B-stride loads from det.
// ---------------------------------------------------------------------------
__global__ void k_mask(const float4* __restrict__ kb4, float* __restrict__ mask) {
  __shared__ float lx1[MAXI], lx2[MAXI];
  __shared__ unsigned long long wmask[4];
  int x = blockIdx.x;
  int h = x & (HH - 1);
  int b = x >> 9;
  int tid = threadIdx.x;
  int wv = tid >> 6, ln = tid & 63;
  float ys = ((float)h + 0.5f) * (1.0f / 512.0f);
  bool inb = false;
  float bx1 = 0.f, bx2 = 0.f;
  if (tid < MAXI) {
    float4 bx = kb4[(size_t)b * MAXI + tid];
    bx1 = bx.y; bx2 = bx.w;
    inb = (ys >= bx.x && ys < bx.z);   // zero (padded) boxes cover nothing
  }
  unsigned long long bm = __ballot(inb);
  if (ln == 0) wmask[wv] = bm;
  __syncthreads();
  int n = __popcll(wmask[0]) + __popcll(wmask[1]);  // tid<100 only in waves 0,1
  if (inb) {
    int pos = (wv ? __popcll(wmask[0]) : 0) +
              __popcll(bm & ((1ULL << ln) - 1ULL));
    lx1[pos] = bx1; lx2[pos] = bx2;
  }
  __syncthreads();
  float xs0 = ((float)tid + 0.5f) * (1.0f / 512.0f);
  float xs1 = ((float)(tid + 256) + 0.5f) * (1.0f / 512.0f);
  bool c0 = false, c1 = false;
  for (int t = 0; t < n; t++) {
    float a = lx1[t], bq = lx2[t];
    c0 = c0 || (xs0 >= a && xs0 < bq);
    c1 = c1 || (xs1 >= a && xs1 < bq);
  }
  float* row = mask + ((size_t)b * HH + h) * WW;
  row[tid] = c0 ? 1.0f : 0.0f;
  row[tid + 256] = c1 ? 1.0f : 0.0f;
}

// ---------------------------------------------------------------------------
extern "C" void kernel_launch(void* const* d_in, const int* in_sizes, int n_in,
                              void* d_out, int out_size, void* d_ws, size_t ws_size,
                              hipStream_t stream) {
  const float* rois = (const float*)d_in[0];
  const float* probs = (const float*)d_in[1];
  const float* deltas = (const float*)d_in[2];
  const float* stdv = (const float*)d_in[3];
  float* out = (float*)d_out;
  float* det = out;                  // [8,100,6] = 4800 floats
  float* mask = out + BB * MAXI * 6; // [8,512,512]

  char* p = (char*)d_ws;
  unsigned long long* gkeys = (unsigned long long*)p; p += (size_t)BB * NPAD * 8;
  float4* pkd = (float4*)p; p += (size_t)BB * NPAD * 32;   // 2 x float4 / slot
  int*    rnk = (int*)p;    p += (size_t)BB * NPAD * 4;
  float4* kb4 = (float4*)p; p += (size_t)BB * MAXI * 16;

  k_refine<<<(BB * NPAD) / 4, 256, 0, stream>>>(rois, probs, deltas, stdv,
                                                pkd, rnk, gkeys);
  k_rankp<<<BB * 64, 256, 0, stream>>>(gkeys, rnk);
  k_permnms<<<BB, 1024, 0, stream>>>(rnk, pkd, det, kb4);
  k_mask<<<BB * HH, 256, 0, stream>>>(kb4, mask);
}